// Round 11
// baseline (223.362 us; speedup 1.0000x reference)
//
#include <hip/hip_runtime.h>
#include <cstdint>
#include <cstddef>

typedef unsigned short u16;
typedef short short8 __attribute__((ext_vector_type(8)));
typedef float floatx4 __attribute__((ext_vector_type(4)));

__device__ __forceinline__ float bf2f(u16 u) {
    union { unsigned int i; float f; } v; v.i = ((unsigned int)u) << 16; return v.f;
}
__device__ __forceinline__ u16 f2bf(float f) {
    union { float f; unsigned int i; } v; v.f = f;
    unsigned int u = v.i;
    return (u16)((u + 0x7fffu + ((u >> 16) & 1u)) >> 16);
}

#if __has_builtin(__builtin_amdgcn_exp2f)
#define EXP2F(x) __builtin_amdgcn_exp2f(x)
#else
#define EXP2F(x) exp2f(x)
#endif

// async global->LDS, 16B per lane; LDS dest = wave-uniform base + lane*16
__device__ __forceinline__ void gload_lds16(const u16* g, void* lds_wave_base) {
    __builtin_amdgcn_global_load_lds(
        (__attribute__((address_space(1))) void*)g,
        (__attribute__((address_space(3))) void*)lds_wave_base,
        16, 0, 0);
}

// counted-vmcnt barrier pair (T4)
#define WAITVM(N) asm volatile("s_waitcnt vmcnt(" #N ")" ::: "memory")
#define BARRIER_ACQ()                      \
    do {                                   \
        __builtin_amdgcn_s_barrier();      \
        asm volatile("" ::: "memory");     \
        __builtin_amdgcn_sched_barrier(0); \
    } while (0)
#define BARRIER_REL()                      \
    do {                                   \
        asm volatile("" ::: "memory");     \
        __builtin_amdgcn_s_barrier();      \
    } while (0)

// ---------------------------------------------------------------------------
// Convert+transpose 4 weight matrices (E x E, f32) -> bf16. Wt[n][k]=W[k][n].
// Matrix 0 (Wq) pre-scaled by log2(e)/32 -> attention uses exp2(S) directly.
// ---------------------------------------------------------------------------
__global__ void conv_transpose_k(const float* __restrict__ w0, const float* __restrict__ w1,
                                 const float* __restrict__ w2, const float* __restrict__ w3,
                                 u16* __restrict__ o0, u16* __restrict__ o1,
                                 u16* __restrict__ o2, u16* __restrict__ o3, int n) {
    __shared__ float t[32][33];
    const float* w; u16* o;
    switch (blockIdx.z) {
        case 0: w = w0; o = o0; break;
        case 1: w = w1; o = o1; break;
        case 2: w = w2; o = o2; break;
        default: w = w3; o = o3; break;
    }
    const float sc = (blockIdx.z == 0) ? 0.04508422f : 1.0f;  // log2(e)/32 on Wq
    int tx = threadIdx.x, ty = threadIdx.y;
    int x0 = blockIdx.x * 32, y0 = blockIdx.y * 32;
    t[ty][tx] = w[(size_t)(y0 + ty) * n + x0 + tx];
    __syncthreads();
    o[(size_t)(x0 + ty) * n + y0 + tx] = f2bf(t[tx][ty] * sc);
}

// ---------------------------------------------------------------------------
// Convert f32 -> bf16, vectorized.
// ---------------------------------------------------------------------------
__global__ void conv_k(const float* __restrict__ in, u16* __restrict__ out, int n) {
    int i = (blockIdx.x * blockDim.x + threadIdx.x) * 4;
    if (i >= n) return;
    float4 v = *(const float4*)&in[i];
    ushort4 o;
    o.x = f2bf(v.x); o.y = f2bf(v.y); o.z = f2bf(v.z); o.w = f2bf(v.w);
    *(ushort4*)&out[i] = o;
}

// ---------------------------------------------------------------------------
// Fused QKV GEMM v3 (unchanged, proven): counted-vmcnt pipeline, LDS-staged
// coalesced epilogue, V stored directly packed [bh][kblk][d][tloc].
// ---------------------------------------------------------------------------
#define QSTG(K0, BUF)                                                          \
    {                                                                          \
        _Pragma("unroll")                                                      \
        for (int it = 0; it < 2; ++it) {                                       \
            int idx = it * 256 + tid;                                          \
            int row = idx >> 2;                                                \
            int c8 = (idx & 3) * 8;                                            \
            size_t ldsoff = (size_t)(it * 256 + wave * 64) * 16;               \
            gload_lds16(&A[(size_t)(bm + row) * K + (K0) + c8],                \
                        (char*)smem + (BUF) * 8192 + ldsoff);                  \
            gload_lds16(&Bt[(size_t)(bn + row) * K + (K0) + c8],               \
                        (char*)smem + 16384 + (BUF) * 8192 + ldsoff);          \
        }                                                                      \
    }

__global__ __launch_bounds__(256, 3) void gemm_qkv(
    const u16* __restrict__ A, const u16* __restrict__ Bt,
    u16* __restrict__ qpk, u16* __restrict__ kpk, u16* __restrict__ vpk,
    int M, int T, int K) {
    __shared__ __align__(16) u16 smem[16384];

    const int tid = threadIdx.x;
    const int lane = tid & 63, wave = tid >> 6;
    const int wm = (wave >> 1) * 64, wn = (wave & 1) * 64;
    const int bm = blockIdx.x * 128, bn = blockIdx.y * 128;
    const int l15 = lane & 15, lq = lane >> 4;

    const int sec = bn >> 10;
    u16* dst = (sec == 0) ? qpk : (sec == 1) ? kpk : vpk;
    const int bnE = bn & 1023;

    floatx4 acc[4][4];
#pragma unroll
    for (int i = 0; i < 4; ++i)
#pragma unroll
        for (int j = 0; j < 4; ++j) acc[i][j] = (floatx4)0.0f;

    const int nkt = K / 32;
    QSTG(0, 0);

    for (int kt = 0; kt < nkt; ++kt) {
        const int cur = kt & 1;
        if (kt + 1 < nkt) {
            QSTG((kt + 1) * 32, cur ^ 1);
            WAITVM(4);
        } else {
            WAITVM(0);
        }
        BARRIER_ACQ();

        const u16* la = smem + cur * 4096;
        const u16* lb = smem + 8192 + cur * 4096;
        short8 af[4], bfr[4];
#pragma unroll
        for (int i = 0; i < 4; ++i) af[i] = *(const short8*)&la[(wm + i * 16 + l15) * 32 + lq * 8];
#pragma unroll
        for (int j = 0; j < 4; ++j) bfr[j] = *(const short8*)&lb[(wn + j * 16 + l15) * 32 + lq * 8];

#pragma unroll
        for (int i = 0; i < 4; ++i)
#pragma unroll
            for (int j = 0; j < 4; ++j)
                acc[i][j] = __builtin_amdgcn_mfma_f32_16x16x32_bf16(af[i], bfr[j], acc[i][j], 0, 0, 0);

        BARRIER_REL();
    }

    if (sec < 2) {
#pragma unroll
        for (int i = 0; i < 4; ++i)
#pragma unroll
            for (int r = 0; r < 4; ++r) {
                int trow = wm + i * 16 + lq * 4 + r;
                int s7 = ((trow >> 2) & 7) << 4;
#pragma unroll
                for (int j = 0; j < 4; ++j) {
                    int col = wn + j * 16 + l15;
                    smem[trow * 128 + (col ^ s7)] = f2bf(acc[i][j][r]);
                }
            }
        __syncthreads();
        const int rg = tid >> 3, cc = tid & 7;
#pragma unroll
        for (int p = 0; p < 4; ++p)
#pragma unroll
            for (int sfx = 0; sfx < 2; ++sfx) {
                int row = p * 32 + rg;
                int ch = cc + sfx * 8;
                short8 v = *(const short8*)&smem[row * 128 + ((ch * 8) ^ (((row >> 2) & 7) << 4))];
                int colE = bnE + ch * 8;
                int h = colE >> 6, d = colE & 63;
                int rowg = bm + row;
                int b = rowg >> 11, t = rowg & 2047;
                *(short8*)&dst[(((size_t)(b * 16 + h) * T) + t) * 64 + d] = v;
            }
    } else {
#pragma unroll
        for (int j = 0; j < 4; ++j) {
            int clo = wn + j * 16 + l15;
            int s7 = ((clo >> 2) & 7) << 4;
#pragma unroll
            for (int i = 0; i < 4; ++i)
#pragma unroll
                for (int r = 0; r < 4; ++r) {
                    int trow = wm + i * 16 + lq * 4 + r;
                    smem[clo * 128 + (trow ^ s7)] = f2bf(acc[i][j][r]);
                }
        }
        __syncthreads();
        const int rg = tid >> 3, cc = tid & 7;
        const int b = bm >> 11;
#pragma unroll
        for (int p = 0; p < 4; ++p)
#pragma unroll
            for (int sfx = 0; sfx < 2; ++sfx) {
                int clo = p * 32 + rg;
                int ch = cc + sfx * 8;
                short8 v = *(const short8*)&smem[clo * 128 + ((ch * 8) ^ (((clo >> 2) & 7) << 4))];
                int colE = bnE + clo;
                int h = colE >> 6, d = colE & 63;
                int t = (bm + ch * 8) & 2047;
                int kblk = t >> 6, tloc = t & 63;
                *(short8*)&dst[(((size_t)(b * 16 + h) * 32 + kblk) * 64 + d) * 64 + tloc] = v;
            }
    }
}

// ---------------------------------------------------------------------------
// FF GEMM v3 (unchanged, proven).
// ---------------------------------------------------------------------------
#define FSTG(K0, BUF)                                                          \
    {                                                                          \
        {                                                                      \
            int row = tid >> 2;                                                \
            int c8 = (tid & 3) * 8;                                            \
            size_t ldsoff = (size_t)(wave * 64) * 16;                          \
            gload_lds16(&A[(size_t)(bm + row) * K + (K0) + c8],                \
                        (char*)smemF + (BUF) * 4096 + ldsoff);                 \
        }                                                                      \
        _Pragma("unroll")                                                      \
        for (int it = 0; it < 2; ++it) {                                       \
            int idx = it * 256 + tid;                                          \
            int row = idx >> 2;                                                \
            int c8 = (idx & 3) * 8;                                            \
            size_t ldsoff = (size_t)(it * 256 + wave * 64) * 16;               \
            gload_lds16(&Bt[(size_t)(bn + row) * K + (K0) + c8],               \
                        (char*)smemF + 8192 + (BUF) * 8192 + ldsoff);          \
        }                                                                      \
    }

__global__ __launch_bounds__(256) void gemm64_bt(
    const u16* __restrict__ A, const u16* __restrict__ Bt, float* __restrict__ Cf,
    const float* __restrict__ bias, const u16* __restrict__ resid,
    int M, int N, int K) {
    __shared__ __align__(16) u16 smemF[12288];

    const int tid = threadIdx.x;
    const int lane = tid & 63, wave = tid >> 6;
    const int wm = (wave >> 1) * 32, wn = (wave & 1) * 64;
    const int bm = blockIdx.x * 64, bn = blockIdx.y * 128;
    const int l15 = lane & 15, lq = lane >> 4;

    floatx4 acc[2][4];
#pragma unroll
    for (int i = 0; i < 2; ++i)
#pragma unroll
        for (int j = 0; j < 4; ++j) acc[i][j] = (floatx4)0.0f;

    const int nkt = K / 32;
    FSTG(0, 0);

    for (int kt = 0; kt < nkt; ++kt) {
        const int cur = kt & 1;
        if (kt + 1 < nkt) {
            FSTG((kt + 1) * 32, cur ^ 1);
            WAITVM(3);
        } else {
            WAITVM(0);
        }
        BARRIER_ACQ();

        const u16* la = smemF + cur * 2048;
        const u16* lb = smemF + 4096 + cur * 2048 * 2;
        short8 af[2], bfr[4];
#pragma unroll
        for (int i = 0; i < 2; ++i) af[i] = *(const short8*)&la[(wm + i * 16 + l15) * 32 + lq * 8];
#pragma unroll
        for (int j = 0; j < 4; ++j) bfr[j] = *(const short8*)&lb[(wn + j * 16 + l15) * 32 + lq * 8];

#pragma unroll
        for (int i = 0; i < 2; ++i)
#pragma unroll
            for (int j = 0; j < 4; ++j)
                acc[i][j] = __builtin_amdgcn_mfma_f32_16x16x32_bf16(af[i], bfr[j], acc[i][j], 0, 0, 0);

        BARRIER_REL();
    }

#pragma unroll
    for (int i = 0; i < 2; ++i)
#pragma unroll
        for (int j = 0; j < 4; ++j)
#pragma unroll
            for (int r = 0; r < 4; ++r) {
                int row = bm + wm + i * 16 + lq * 4 + r;
                int col = bn + wn + j * 16 + l15;
                float v = acc[i][j][r];
                v = fmaxf(v + bias[col], 0.0f) + bf2f(resid[(size_t)row * N + col]);
                Cf[(size_t)row * N + col] = v;
            }
}

// ---------------------------------------------------------------------------
// Flash attention v20 = attn11 body with a 128-row K window (double-buffered,
// SAME 32 KB LDS) and V read directly from global (attn12's verified V path).
// Per barrier window: 32 MFMA (2 x 64-chunk) instead of 16, K staging 4 loads
// (vmcnt(4)), barriers per k-row HALVED — the per-window overhead (~1300 cy)
// identified across rounds 5-10 is amortized over 2x the work with zero
// occupancy loss (grid stays (32,32)=1024 blocks, 4 waves, LPT).
// V rationale (m169): a V-chunk is 8 KB, L2-hot (reused by all 32 q-blocks of
// its head); its loads issue right after the barrier with the whole
// QK+softmax phase of slack — unlike attn12 where the unprefetched K loads
// sat on the critical path. At the window-top WAITVM, all previous V loads
// have completed (compiler inserts waits before their MFMA uses), so
// vmcnt(4) counts only the next window's K staging.
// Swizzle algebra unchanged: rotation key fr(r)=(r&3)|(((r>>3)&1)<<2) is
// invariant under r+32/r+64, so the 4 sub-stages and both 64-row halves use
// the attn11 formulas verbatim.
// ---------------------------------------------------------------------------
#define STAGEK(W, BUF)                                                            \
    {                                                                             \
        const u16* kc_ = kb + (size_t)((W) * 128 + r0) * 64 + swz0;               \
        gload_lds16(kc_,           (char*)kbuf + (BUF) * 16384 + wave * 1024);    \
        gload_lds16(kc_ + 32 * 64, (char*)kbuf + (BUF) * 16384 + 4096 + wave * 1024);  \
        gload_lds16(kc_ + 64 * 64, (char*)kbuf + (BUF) * 16384 + 8192 + wave * 1024);  \
        gload_lds16(kc_ + 96 * 64, (char*)kbuf + (BUF) * 16384 + 12288 + wave * 1024); \
    }

__global__ __launch_bounds__(256) void attn20_k(
    const u16* __restrict__ qpk, const u16* __restrict__ kpk,
    const u16* __restrict__ vpack, const float* __restrict__ xf,
    u16* __restrict__ y, int T, int E) {
    __shared__ u16 kbuf[2][128 * 64];       // K only: 2 x 16 KB, f-swizzled slots

    const int tid = threadIdx.x;
    const int lane = tid & 63, wave = tid >> 6;
    const int l15 = lane & 15, lq = lane >> 4;
    const int bh = blockIdx.x;              // grid.x = 32 -> head-per-XCD affinity
    const int b = bh >> 4, h = bh & 15;
    const int qb = 31 - (int)blockIdx.y;    // LPT: longest blocks dispatch first

    const u16* qp = qpk + (size_t)bh * T * 64;
    const u16* kb = kpk + (size_t)bh * T * 64;
    const u16* vp = vpack + (size_t)bh * T * 64;    // [T/64][64][64] blocks

    const int r0 = tid >> 3;            // staging row 0..31 (per 4K sub-stage)
    const int slot = tid & 7;           // staging 16B slot within row
    const int fr0 = (r0 & 3) | (((r0 >> 3) & 1) << 2);
    const int swz0 = ((slot - fr0) & 7) * 8;        // source col elems (swizzle)

    // K-row permutation: MFMA t2 row i holds k = (i>>2)*8+(t2&1)*4+(i&3)+(t2>>1)*32
    const int rbase = ((l15 >> 2) * 8) + (l15 & 3);
    const int sA = lq + (l15 & 7);                           // K read slot base

    const int qt = qb * 64 + wave * 16;     // this wave's 16 q-rows
    const int qg = qt + l15;                // lane's q-row in S^T layout
    const int nwin = (qb >> 1) + 1;         // 128-row windows

    short8 aq[2];
#pragma unroll
    for (int c = 0; c < 2; ++c)
        aq[c] = *(const short8*)&qp[(size_t)qg * 64 + c * 32 + lq * 8];

    floatx4 o[4];
#pragma unroll
    for (int n = 0; n < 4; ++n) o[n] = (floatx4)0.0f;
    float lsum = 0.0f;

    // prologue: stage window 0 (certified inside the loop)
    STAGEK(0, 0);

#pragma unroll 1
    for (int w = 0; w < nwin; ++w) {
        const int cur = w & 1;
        const int curoff = cur * 32768;  // byte offset into kbuf

        // stage next K window, wait only for the current one (V loads from
        // previous windows are already complete: compiler waits before use)
        if (w + 1 < nwin) {
            STAGEK(w + 1, cur ^ 1);
            WAITVM(4);
        } else {
            WAITVM(0);
        }
        BARRIER_ACQ();

#pragma unroll
        for (int sub = 0; sub < 2; ++sub) {
            const int kt64 = 2 * w + sub;       // 64-chunk index
            if (kt64 > qb) continue;            // block-uniform causal skip
            const int kc0 = kt64 * 64;
            const int suboff = curoff + sub * 8192;

            // ---- S^T = K Q^T (rows = permuted k, cols = q) ----
            floatx4 st[4];
            __builtin_amdgcn_s_setprio(1);
#pragma unroll
            for (int t2 = 0; t2 < 4; ++t2) {
                const int row = rbase + (t2 & 1) * 4 + (t2 >> 1) * 32;
                floatx4 sa = (floatx4)0.0f;
#pragma unroll
                for (int c = 0; c < 2; ++c) {
                    int off = row * 128 + ((c * 4 + sA) & 7) * 16;
                    short8 bk = *(const short8*)((const char*)kbuf + suboff + off);
                    sa = __builtin_amdgcn_mfma_f32_16x16x32_bf16(bk, aq[c], sa, 0, 0, 0);
                }
                st[t2] = sa;
            }
            __builtin_amdgcn_s_setprio(0);

            // ---- softmax numerator (Q pre-scaled -> exp2 direct) ----
            const bool partial = (kt64 == qb);
            unsigned int pw[8];
#pragma unroll
            for (int t2 = 0; t2 < 4; ++t2) {
                float e0, e1, e2, e3;
                const int kg0 = kc0 + lq * 8 + (t2 & 1) * 4 + ((t2 >> 1) * 32);
                if (partial) {
                    e0 = (kg0 + 0 <= qg) ? EXP2F(st[t2][0]) : 0.0f;
                    e1 = (kg0 + 1 <= qg) ? EXP2F(st[t2][1]) : 0.0f;
                    e2 = (kg0 + 2 <= qg) ? EXP2F(st[t2][2]) : 0.0f;
                    e3 = (kg0 + 3 <= qg) ? EXP2F(st[t2][3]) : 0.0f;
                } else {
                    e0 = EXP2F(st[t2][0]);
                    e1 = EXP2F(st[t2][1]);
                    e2 = EXP2F(st[t2][2]);
                    e3 = EXP2F(st[t2][3]);
                }
                lsum += (e0 + e1) + (e2 + e3);
                unsigned int w0, w1;
                asm("v_cvt_pk_bf16_f32 %0, %1, %2" : "=v"(w0) : "v"(e0), "v"(e1));
                asm("v_cvt_pk_bf16_f32 %0, %1, %2" : "=v"(w1) : "v"(e2), "v"(e3));
                pw[t2 * 2 + 0] = w0;
                pw[t2 * 2 + 1] = w1;
            }

            // ---- O += P @ V (V straight from global: L2-hot packed chunks) ----
            __builtin_amdgcn_s_setprio(1);
#pragma unroll
            for (int kc = 0; kc < 2; ++kc) {
                union { unsigned int u[4]; short8 s; } ap;
                ap.u[0] = pw[kc * 4 + 0];
                ap.u[1] = pw[kc * 4 + 1];
                ap.u[2] = pw[kc * 4 + 2];
                ap.u[3] = pw[kc * 4 + 3];
#pragma unroll
                for (int n = 0; n < 4; ++n) {
                    short8 bv = *(const short8*)&vp[(size_t)kt64 * 4096 + (n * 16 + l15) * 64 + kc * 32 + lq * 8];
                    o[n] = __builtin_amdgcn_mfma_f32_16x16x32_bf16(ap.s, bv, o[n], 0, 0, 0);
                }
            }
            __builtin_amdgcn_s_setprio(0);
        }

        BARRIER_REL();   // readers of kbuf[cur] done before next overwrite
    }

    // ---- row-sum reduce across lq groups + redistribute to O rows ----
    lsum += __shfl_xor(lsum, 16, 64);
    lsum += __shfl_xor(lsum, 32, 64);

    const float* xp = xf + (size_t)b * T * E + (size_t)h * 64;
    u16* yp = y + (size_t)b * T * E + (size_t)h * 64;
    float rl[4];
#pragma unroll
    for (int r = 0; r < 4; ++r) rl[r] = 1.0f / __shfl(lsum, lq * 4 + r, 64);
#pragma unroll
    for (int n = 0; n < 4; ++n)
#pragma unroll
        for (int r = 0; r < 4; ++r) {
            int rowg = qt + lq * 4 + r;
            int col = n * 16 + l15;
            float val = o[n][r] * rl[r];
            float res = __builtin_nontemporal_load(xp + (size_t)rowg * E + col);
            yp[(size_t)rowg * E + col] = f2bf(res + val);
        }
}

// ---------------------------------------------------------------------------
extern "C" void kernel_launch(void* const* d_in, const int* in_sizes, int n_in,
                              void* d_out, int out_size, void* d_ws, size_t ws_size,
                              hipStream_t stream) {
    const int B = 2, T = 2048, E = 1024;
    const int M = B * T;  // 4096

    const float* x  = (const float*)d_in[0];
    const float* Wq = (const float*)d_in[1];
    const float* Wk = (const float*)d_in[2];
    const float* Wv = (const float*)d_in[3];
    const float* Wf = (const float*)d_in[4];
    const float* bf = (const float*)d_in[5];
    float* out = (float*)d_out;

    u16* ws = (u16*)d_ws;
    const size_t WN = (size_t)E * E;
    const size_t XN = (size_t)M * E;
    u16* Wqkv  = ws;
    u16* WfT   = ws + 3 * WN;
    u16* xb    = ws + 4 * WN;
    u16* qpk   = ws + 4 * WN + XN;
    u16* kpk   = ws + 4 * WN + 2 * XN;
    u16* vpk   = ws + 4 * WN + 3 * XN;
    u16* yb    = ws + 4 * WN + 4 * XN;
    // total: 4*WN + 5*XN = 48 MB

    conv_transpose_k<<<dim3(E / 32, E / 32, 4), dim3(32, 32), 0, stream>>>(
        Wq, Wk, Wv, Wf, Wqkv, Wqkv + WN, Wqkv + 2 * WN, WfT, E);
    conv_k<<<(int)(XN / 1024), 256, 0, stream>>>(x, xb, (int)XN);

    gemm_qkv<<<dim3(M / 128, 3 * E / 128), 256, 0, stream>>>(
        xb, Wqkv, qpk, kpk, vpk, M, T, E);

    // grid (bh=32, qb=32), 256 threads, LPT; 128-row K windows, V from L2
    attn20_k<<<dim3(B * 16, T / 64), 256, 0, stream>>>(qpk, kpk, vpk, x, yb, T, E);

    gemm64_bt<<<dim3(M / 64, E / 128), 256, 0, stream>>>(yb, WfT, out, bf, yb, M, E, E);
}

// Round 12
// 179.696 us; speedup vs baseline: 1.2430x; 1.2430x over previous
//
#include <hip/hip_runtime.h>
#include <cstdint>
#include <cstddef>

typedef unsigned short u16;
typedef short short8 __attribute__((ext_vector_type(8)));
typedef float floatx4 __attribute__((ext_vector_type(4)));

__device__ __forceinline__ float bf2f(u16 u) {
    union { unsigned int i; float f; } v; v.i = ((unsigned int)u) << 16; return v.f;
}
__device__ __forceinline__ u16 f2bf(float f) {
    union { float f; unsigned int i; } v; v.f = f;
    unsigned int u = v.i;
    return (u16)((u + 0x7fffu + ((u >> 16) & 1u)) >> 16);
}

#if __has_builtin(__builtin_amdgcn_exp2f)
#define EXP2F(x) __builtin_amdgcn_exp2f(x)
#else
#define EXP2F(x) exp2f(x)
#endif

// async global->LDS, 16B per lane; LDS dest = wave-uniform base + lane*16
__device__ __forceinline__ void gload_lds16(const u16* g, void* lds_wave_base) {
    __builtin_amdgcn_global_load_lds(
        (__attribute__((address_space(1))) void*)g,
        (__attribute__((address_space(3))) void*)lds_wave_base,
        16, 0, 0);
}

// counted-vmcnt barrier pair (T4)
#define WAITVM(N) asm volatile("s_waitcnt vmcnt(" #N ")" ::: "memory")
#define BARRIER_ACQ()                      \
    do {                                   \
        __builtin_amdgcn_s_barrier();      \
        asm volatile("" ::: "memory");     \
        __builtin_amdgcn_sched_barrier(0); \
    } while (0)
#define BARRIER_REL()                      \
    do {                                   \
        asm volatile("" ::: "memory");     \
        __builtin_amdgcn_s_barrier();      \
    } while (0)

// ---------------------------------------------------------------------------
// Convert+transpose 4 weight matrices (E x E, f32) -> bf16. Wt[n][k]=W[k][n].
// Matrix 0 (Wq) pre-scaled by log2(e)/32 -> attention uses exp2(S) directly.
// ---------------------------------------------------------------------------
__global__ void conv_transpose_k(const float* __restrict__ w0, const float* __restrict__ w1,
                                 const float* __restrict__ w2, const float* __restrict__ w3,
                                 u16* __restrict__ o0, u16* __restrict__ o1,
                                 u16* __restrict__ o2, u16* __restrict__ o3, int n) {
    __shared__ float t[32][33];
    const float* w; u16* o;
    switch (blockIdx.z) {
        case 0: w = w0; o = o0; break;
        case 1: w = w1; o = o1; break;
        case 2: w = w2; o = o2; break;
        default: w = w3; o = o3; break;
    }
    const float sc = (blockIdx.z == 0) ? 0.04508422f : 1.0f;  // log2(e)/32 on Wq
    int tx = threadIdx.x, ty = threadIdx.y;
    int x0 = blockIdx.x * 32, y0 = blockIdx.y * 32;
    t[ty][tx] = w[(size_t)(y0 + ty) * n + x0 + tx];
    __syncthreads();
    o[(size_t)(x0 + ty) * n + y0 + tx] = f2bf(t[tx][ty] * sc);
}

// ---------------------------------------------------------------------------
// Convert f32 -> bf16, vectorized.
// ---------------------------------------------------------------------------
__global__ void conv_k(const float* __restrict__ in, u16* __restrict__ out, int n) {
    int i = (blockIdx.x * blockDim.x + threadIdx.x) * 4;
    if (i >= n) return;
    float4 v = *(const float4*)&in[i];
    ushort4 o;
    o.x = f2bf(v.x); o.y = f2bf(v.y); o.z = f2bf(v.z); o.w = f2bf(v.w);
    *(ushort4*)&out[i] = o;
}

// ---------------------------------------------------------------------------
// Fused QKV GEMM v4 = v3 (proven: counted-vmcnt pipeline, LDS-staged
// coalesced epilogue, V stored packed) + T1 XCD-aware block swizzle:
// 768 blocks, chunked remap swz=(lin&7)*96+(lin>>3) gives each XCD 3 whole
// 128-col weight panels (was: every panel round-robined across all 8 XCDs'
// L2s). Bijective (768%8==0).
// ---------------------------------------------------------------------------
#define QSTG(K0, BUF)                                                          \
    {                                                                          \
        _Pragma("unroll")                                                      \
        for (int it = 0; it < 2; ++it) {                                       \
            int idx = it * 256 + tid;                                          \
            int row = idx >> 2;                                                \
            int c8 = (idx & 3) * 8;                                            \
            size_t ldsoff = (size_t)(it * 256 + wave * 64) * 16;               \
            gload_lds16(&A[(size_t)(bm + row) * K + (K0) + c8],                \
                        (char*)smem + (BUF) * 8192 + ldsoff);                  \
            gload_lds16(&Bt[(size_t)(bn + row) * K + (K0) + c8],               \
                        (char*)smem + 16384 + (BUF) * 8192 + ldsoff);          \
        }                                                                      \
    }

__global__ __launch_bounds__(256, 3) void gemm_qkv(
    const u16* __restrict__ A, const u16* __restrict__ Bt,
    u16* __restrict__ qpk, u16* __restrict__ kpk, u16* __restrict__ vpk,
    int M, int T, int K) {
    __shared__ __align__(16) u16 smem[16384];

    const int tid = threadIdx.x;
    const int lane = tid & 63, wave = tid >> 6;
    const int wm = (wave >> 1) * 64, wn = (wave & 1) * 64;

    // T1 XCD swizzle: lin = bx + 32*by over (32,24); XCD = lin%8 under
    // dispatch order -> remap so each XCD gets 96 contiguous work-ids
    // (= 3 full weight panels).
    const int lin = (int)blockIdx.x + ((int)blockIdx.y << 5);
    const int swz = (lin & 7) * 96 + (lin >> 3);
    const int bm = (swz & 31) * 128, bn = (swz >> 5) * 128;

    const int l15 = lane & 15, lq = lane >> 4;

    const int sec = bn >> 10;
    u16* dst = (sec == 0) ? qpk : (sec == 1) ? kpk : vpk;
    const int bnE = bn & 1023;

    floatx4 acc[4][4];
#pragma unroll
    for (int i = 0; i < 4; ++i)
#pragma unroll
        for (int j = 0; j < 4; ++j) acc[i][j] = (floatx4)0.0f;

    const int nkt = K / 32;
    QSTG(0, 0);

    for (int kt = 0; kt < nkt; ++kt) {
        const int cur = kt & 1;
        if (kt + 1 < nkt) {
            QSTG((kt + 1) * 32, cur ^ 1);
            WAITVM(4);
        } else {
            WAITVM(0);
        }
        BARRIER_ACQ();

        const u16* la = smem + cur * 4096;
        const u16* lb = smem + 8192 + cur * 4096;
        short8 af[4], bfr[4];
#pragma unroll
        for (int i = 0; i < 4; ++i) af[i] = *(const short8*)&la[(wm + i * 16 + l15) * 32 + lq * 8];
#pragma unroll
        for (int j = 0; j < 4; ++j) bfr[j] = *(const short8*)&lb[(wn + j * 16 + l15) * 32 + lq * 8];

#pragma unroll
        for (int i = 0; i < 4; ++i)
#pragma unroll
            for (int j = 0; j < 4; ++j)
                acc[i][j] = __builtin_amdgcn_mfma_f32_16x16x32_bf16(af[i], bfr[j], acc[i][j], 0, 0, 0);

        BARRIER_REL();
    }

    if (sec < 2) {
#pragma unroll
        for (int i = 0; i < 4; ++i)
#pragma unroll
            for (int r = 0; r < 4; ++r) {
                int trow = wm + i * 16 + lq * 4 + r;
                int s7 = ((trow >> 2) & 7) << 4;
#pragma unroll
                for (int j = 0; j < 4; ++j) {
                    int col = wn + j * 16 + l15;
                    smem[trow * 128 + (col ^ s7)] = f2bf(acc[i][j][r]);
                }
            }
        __syncthreads();
        const int rg = tid >> 3, cc = tid & 7;
#pragma unroll
        for (int p = 0; p < 4; ++p)
#pragma unroll
            for (int sfx = 0; sfx < 2; ++sfx) {
                int row = p * 32 + rg;
                int ch = cc + sfx * 8;
                short8 v = *(const short8*)&smem[row * 128 + ((ch * 8) ^ (((row >> 2) & 7) << 4))];
                int colE = bnE + ch * 8;
                int h = colE >> 6, d = colE & 63;
                int rowg = bm + row;
                int b = rowg >> 11, t = rowg & 2047;
                *(short8*)&dst[(((size_t)(b * 16 + h) * T) + t) * 64 + d] = v;
            }
    } else {
#pragma unroll
        for (int j = 0; j < 4; ++j) {
            int clo = wn + j * 16 + l15;
            int s7 = ((clo >> 2) & 7) << 4;
#pragma unroll
            for (int i = 0; i < 4; ++i)
#pragma unroll
                for (int r = 0; r < 4; ++r) {
                    int trow = wm + i * 16 + lq * 4 + r;
                    smem[clo * 128 + (trow ^ s7)] = f2bf(acc[i][j][r]);
                }
        }
        __syncthreads();
        const int rg = tid >> 3, cc = tid & 7;
        const int b = bm >> 11;
#pragma unroll
        for (int p = 0; p < 4; ++p)
#pragma unroll
            for (int sfx = 0; sfx < 2; ++sfx) {
                int clo = p * 32 + rg;
                int ch = cc + sfx * 8;
                short8 v = *(const short8*)&smem[clo * 128 + ((ch * 8) ^ (((clo >> 2) & 7) << 4))];
                int colE = bnE + clo;
                int h = colE >> 6, d = colE & 63;
                int t = (bm + ch * 8) & 2047;
                int kblk = t >> 6, tloc = t & 63;
                *(short8*)&dst[(((size_t)(b * 16 + h) * 32 + kblk) * 64 + d) * 64 + tloc] = v;
            }
    }
}

// ---------------------------------------------------------------------------
// FF GEMM v4 = v3 (proven) + T1 XCD swizzle: 512 blocks, swz=(lin&7)*64+
// (lin>>3) -> each XCD owns exactly ONE 128-col Wf panel (perfect B-panel
// L2 locality). Bijective (512%8==0).
// ---------------------------------------------------------------------------
#define FSTG(K0, BUF)                                                          \
    {                                                                          \
        {                                                                      \
            int row = tid >> 2;                                                \
            int c8 = (tid & 3) * 8;                                            \
            size_t ldsoff = (size_t)(wave * 64) * 16;                          \
            gload_lds16(&A[(size_t)(bm + row) * K + (K0) + c8],                \
                        (char*)smemF + (BUF) * 4096 + ldsoff);                 \
        }                                                                      \
        _Pragma("unroll")                                                      \
        for (int it = 0; it < 2; ++it) {                                       \
            int idx = it * 256 + tid;                                          \
            int row = idx >> 2;                                                \
            int c8 = (idx & 3) * 8;                                            \
            size_t ldsoff = (size_t)(it * 256 + wave * 64) * 16;               \
            gload_lds16(&Bt[(size_t)(bn + row) * K + (K0) + c8],               \
                        (char*)smemF + 8192 + (BUF) * 8192 + ldsoff);          \
        }                                                                      \
    }

__global__ __launch_bounds__(256) void gemm64_bt(
    const u16* __restrict__ A, const u16* __restrict__ Bt, float* __restrict__ Cf,
    const float* __restrict__ bias, const u16* __restrict__ resid,
    int M, int N, int K) {
    __shared__ __align__(16) u16 smemF[12288];

    const int tid = threadIdx.x;
    const int lane = tid & 63, wave = tid >> 6;
    const int wm = (wave >> 1) * 32, wn = (wave & 1) * 64;

    // T1 XCD swizzle over (64,8): each XCD gets 64 contiguous ids = one panel
    const int lin = (int)blockIdx.x + ((int)blockIdx.y << 6);
    const int swz = (lin & 7) * 64 + (lin >> 3);
    const int bm = (swz & 63) * 64, bn = (swz >> 6) * 128;

    const int l15 = lane & 15, lq = lane >> 4;

    floatx4 acc[2][4];
#pragma unroll
    for (int i = 0; i < 2; ++i)
#pragma unroll
        for (int j = 0; j < 4; ++j) acc[i][j] = (floatx4)0.0f;

    const int nkt = K / 32;
    FSTG(0, 0);

    for (int kt = 0; kt < nkt; ++kt) {
        const int cur = kt & 1;
        if (kt + 1 < nkt) {
            FSTG((kt + 1) * 32, cur ^ 1);
            WAITVM(3);
        } else {
            WAITVM(0);
        }
        BARRIER_ACQ();

        const u16* la = smemF + cur * 2048;
        const u16* lb = smemF + 4096 + cur * 2048 * 2;
        short8 af[2], bfr[4];
#pragma unroll
        for (int i = 0; i < 2; ++i) af[i] = *(const short8*)&la[(wm + i * 16 + l15) * 32 + lq * 8];
#pragma unroll
        for (int j = 0; j < 4; ++j) bfr[j] = *(const short8*)&lb[(wn + j * 16 + l15) * 32 + lq * 8];

#pragma unroll
        for (int i = 0; i < 2; ++i)
#pragma unroll
            for (int j = 0; j < 4; ++j)
                acc[i][j] = __builtin_amdgcn_mfma_f32_16x16x32_bf16(af[i], bfr[j], acc[i][j], 0, 0, 0);

        BARRIER_REL();
    }

#pragma unroll
    for (int i = 0; i < 2; ++i)
#pragma unroll
        for (int j = 0; j < 4; ++j)
#pragma unroll
            for (int r = 0; r < 4; ++r) {
                int row = bm + wm + i * 16 + lq * 4 + r;
                int col = bn + wn + j * 16 + l15;
                float v = acc[i][j][r];
                v = fmaxf(v + bias[col], 0.0f) + bf2f(resid[(size_t)row * N + col]);
                Cf[(size_t)row * N + col] = v;
            }
}

// ---------------------------------------------------------------------------
// Flash attention v18 (round-9 best config, UNCHANGED): attn11 body, plain
// LPT qb = 31-by, counted-vmcnt staging, occupancy throttled to 3 blocks/CU
// via +20 KB dynamic LDS (768 slots < 1024 blocks -> backfill sustains
// residency). Nine structural experiments confirmed this as the local
// optimum for this workload.
// ---------------------------------------------------------------------------
#define STAGE(KT, BUF)                                                            \
    {                                                                             \
        const u16* kc_ = kb + (size_t)((KT) * 64 + r0) * 64 + swz0;               \
        gload_lds16(kc_, (char*)kbuf + (BUF) * 8192 + wave * 1024);               \
        gload_lds16(kc_ + 32 * 64, (char*)kbuf + (BUF) * 8192 + 4096 + wave * 1024); \
        const u16* vc_ = vp + (size_t)(KT) * 4096 + r0 * 64 + swz0;               \
        gload_lds16(vc_, (char*)vbuf + (BUF) * 8192 + wave * 1024);               \
        gload_lds16(vc_ + 32 * 64, (char*)vbuf + (BUF) * 8192 + 4096 + wave * 1024); \
    }

__global__ __launch_bounds__(256) void attn18_k(
    const u16* __restrict__ qpk, const u16* __restrict__ kpk,
    const u16* __restrict__ vpack, const float* __restrict__ xf,
    u16* __restrict__ y, int T, int E) {
    __shared__ u16 kbuf[2][64 * 64];        // double-buffered, f-swizzled slots
    __shared__ u16 vbuf[2][64 * 64];
    // +20 KB dynamic LDS requested at launch -> 52 KB/block -> 3 blocks/CU

    const int tid = threadIdx.x;
    const int lane = tid & 63, wave = tid >> 6;
    const int l15 = lane & 15, lq = lane >> 4;
    const int bh = blockIdx.x;              // grid.x = 32 -> head-per-XCD affinity
    const int b = bh >> 4, h = bh & 15;
    const int qb = 31 - (int)blockIdx.y;    // LPT: longest blocks dispatch first

    const u16* qp = qpk + (size_t)bh * T * 64;
    const u16* kb = kpk + (size_t)bh * T * 64;
    const u16* vp = vpack + (size_t)bh * T * 64;    // [T/64][64][64] blocks

    const int r0 = tid >> 3;            // staging row 0..31
    const int slot = tid & 7;           // staging 16B slot within row
    const int fr0 = (r0 & 3) | (((r0 >> 3) & 1) << 2);
    const int swz0 = ((slot - fr0) & 7) * 8;        // source col elems (swizzle)

    // K-row permutation: MFMA t2 row i holds k = (i>>2)*8+(t2&1)*4+(i&3)+(t2>>1)*32
    const int rbase = ((l15 >> 2) * 8) + (l15 & 3);
    const int sA = lq + (l15 & 7);                           // K read slot base
    const int sB = lq + ((l15 & 3) | (((l15 >> 3) & 1) << 2)); // V read slot base

    const int qt = qb * 64 + wave * 16;     // this wave's 16 q-rows
    const int qg = qt + l15;                // lane's q-row in S^T layout
    const int nkb = qb + 1;

    short8 aq[2];
#pragma unroll
    for (int c = 0; c < 2; ++c)
        aq[c] = *(const short8*)&qp[(size_t)qg * 64 + c * 32 + lq * 8];

    floatx4 o[4];
#pragma unroll
    for (int n = 0; n < 4; ++n) o[n] = (floatx4)0.0f;
    float lsum = 0.0f;

    // prologue: stage chunk 0 into buffer 0 (waited inside the loop)
    STAGE(0, 0);

#pragma unroll 1
    for (int kt = 0; kt < nkb; ++kt) {
        const int kc0 = kt * 64;
        const int cur = kt & 1;
        const int curoff = cur * 8192;   // byte offset into kbuf/vbuf

        // issue DMA for next chunk into the alternate buffer, then wait only
        // for the CURRENT chunk's loads (issued a full iteration ago)
        if (kt + 1 < nkb) {
            STAGE(kt + 1, cur ^ 1);
            WAITVM(4);
        } else {
            WAITVM(0);
        }
        BARRIER_ACQ();

        // ---- S^T = K Q^T (rows = permuted k, cols = q) ----
        floatx4 st[4];
        __builtin_amdgcn_s_setprio(1);
#pragma unroll
        for (int t2 = 0; t2 < 4; ++t2) {
            const int row = rbase + (t2 & 1) * 4 + (t2 >> 1) * 32;
            floatx4 sa = (floatx4)0.0f;
#pragma unroll
            for (int c = 0; c < 2; ++c) {
                int off = row * 128 + ((c * 4 + sA) & 7) * 16;
                short8 bk = *(const short8*)((const char*)kbuf + curoff + off);
                sa = __builtin_amdgcn_mfma_f32_16x16x32_bf16(bk, aq[c], sa, 0, 0, 0);
            }
            st[t2] = sa;
        }
        __builtin_amdgcn_s_setprio(0);

        // ---- softmax numerator (Q pre-scaled -> exp2 direct), pack in-reg ----
        const bool partial = (kt == qb);   // block-uniform: only diagonal chunk
        unsigned int pw[8];
#pragma unroll
        for (int t2 = 0; t2 < 4; ++t2) {
            float e0, e1, e2, e3;
            const int kg0 = kc0 + lq * 8 + (t2 & 1) * 4 + ((t2 >> 1) * 32);
            if (partial) {
                e0 = (kg0 + 0 <= qg) ? EXP2F(st[t2][0]) : 0.0f;
                e1 = (kg0 + 1 <= qg) ? EXP2F(st[t2][1]) : 0.0f;
                e2 = (kg0 + 2 <= qg) ? EXP2F(st[t2][2]) : 0.0f;
                e3 = (kg0 + 3 <= qg) ? EXP2F(st[t2][3]) : 0.0f;
            } else {
                e0 = EXP2F(st[t2][0]);
                e1 = EXP2F(st[t2][1]);
                e2 = EXP2F(st[t2][2]);
                e3 = EXP2F(st[t2][3]);
            }
            lsum += (e0 + e1) + (e2 + e3);
            unsigned int w0, w1;
            asm("v_cvt_pk_bf16_f32 %0, %1, %2" : "=v"(w0) : "v"(e0), "v"(e1));
            asm("v_cvt_pk_bf16_f32 %0, %1, %2" : "=v"(w1) : "v"(e2), "v"(e3));
            pw[t2 * 2 + 0] = w0;
            pw[t2 * 2 + 1] = w1;
        }

        // ---- O += P @ V (P already lane-local in A-fragment layout) ----
        __builtin_amdgcn_s_setprio(1);
#pragma unroll
        for (int kc = 0; kc < 2; ++kc) {
            union { unsigned int u[4]; short8 s; } ap;
            ap.u[0] = pw[kc * 4 + 0];
            ap.u[1] = pw[kc * 4 + 1];
            ap.u[2] = pw[kc * 4 + 2];
            ap.u[3] = pw[kc * 4 + 3];
#pragma unroll
            for (int n = 0; n < 4; ++n) {
                int off = (n * 16 + l15) * 128 + ((kc * 4 + sB) & 7) * 16;
                short8 bv = *(const short8*)((const char*)vbuf + curoff + off);
                o[n] = __builtin_amdgcn_mfma_f32_16x16x32_bf16(ap.s, bv, o[n], 0, 0, 0);
            }
        }
        __builtin_amdgcn_s_setprio(0);

        BARRIER_REL();   // readers of buf cur done before next iter overwrites
    }

    // ---- row-sum reduce across lq groups + redistribute to O rows ----
    lsum += __shfl_xor(lsum, 16, 64);
    lsum += __shfl_xor(lsum, 32, 64);

    const float* xp = xf + (size_t)b * T * E + (size_t)h * 64;
    u16* yp = y + (size_t)b * T * E + (size_t)h * 64;
    float rl[4];
#pragma unroll
    for (int r = 0; r < 4; ++r) rl[r] = 1.0f / __shfl(lsum, lq * 4 + r, 64);
#pragma unroll
    for (int n = 0; n < 4; ++n)
#pragma unroll
        for (int r = 0; r < 4; ++r) {
            int rowg = qt + lq * 4 + r;
            int col = n * 16 + l15;
            float val = o[n][r] * rl[r];
            float res = __builtin_nontemporal_load(xp + (size_t)rowg * E + col);
            yp[(size_t)rowg * E + col] = f2bf(res + val);
        }
}

// ---------------------------------------------------------------------------
extern "C" void kernel_launch(void* const* d_in, const int* in_sizes, int n_in,
                              void* d_out, int out_size, void* d_ws, size_t ws_size,
                              hipStream_t stream) {
    const int B = 2, T = 2048, E = 1024;
    const int M = B * T;  // 4096

    const float* x  = (const float*)d_in[0];
    const float* Wq = (const float*)d_in[1];
    const float* Wk = (const float*)d_in[2];
    const float* Wv = (const float*)d_in[3];
    const float* Wf = (const float*)d_in[4];
    const float* bf = (const float*)d_in[5];
    float* out = (float*)d_out;

    u16* ws = (u16*)d_ws;
    const size_t WN = (size_t)E * E;      // 1M elems per weight
    const size_t XN = (size_t)M * E;      // 4M elems per activation
    u16* Wqkv  = ws;                       // [3E][E] fused transposed weights
    u16* WfT   = ws + 3 * WN;
    u16* xb    = ws + 4 * WN;              // A input (bf16 x)
    u16* qpk   = ws + 4 * WN + XN;         // per-head dense q [bh][t][64]
    u16* kpk   = ws + 4 * WN + 2 * XN;     // per-head dense k
    u16* vpk   = ws + 4 * WN + 3 * XN;     // packed v [bh][T/64][64][64]
    u16* yb    = ws + 4 * WN + 4 * XN;
    // total: 4*WN + 5*XN = 48 MB

    conv_transpose_k<<<dim3(E / 32, E / 32, 4), dim3(32, 32), 0, stream>>>(
        Wq, Wk, Wv, Wf, Wqkv, Wqkv + WN, Wqkv + 2 * WN, WfT, E);
    conv_k<<<(int)(XN / 1024), 256, 0, stream>>>(x, xb, (int)XN);

    // fused QKV projection (T1 XCD-swizzled): q/k per-head dense, v packed
    gemm_qkv<<<dim3(M / 128, 3 * E / 128), 256, 0, stream>>>(
        xb, Wqkv, qpk, kpk, vpk, M, T, E);

    // grid (bh=32, qb=32), LPT; +20 KB dynamic LDS throttles to 3 blocks/CU
    // (768 slots < 1024 blocks -> backfill sustains residency)
    attn18_k<<<dim3(B * 16, T / 64), 256, 20480, stream>>>(qpk, kpk, vpk, x, yb, T, E);

    // FF (T1 XCD-swizzled): out = yb + relu(yb @ Wf + bf)
    gemm64_bt<<<dim3(M / 64, E / 128), 256, 0, stream>>>(yb, WfT, out, bf, yb, M, E, E);
}

// Round 13
// 173.800 us; speedup vs baseline: 1.2852x; 1.0339x over previous
//
#include <hip/hip_runtime.h>
#include <cstdint>
#include <cstddef>

typedef unsigned short u16;
typedef short short8 __attribute__((ext_vector_type(8)));
typedef float floatx4 __attribute__((ext_vector_type(4)));

__device__ __forceinline__ float bf2f(u16 u) {
    union { unsigned int i; float f; } v; v.i = ((unsigned int)u) << 16; return v.f;
}
__device__ __forceinline__ u16 f2bf(float f) {
    union { float f; unsigned int i; } v; v.f = f;
    unsigned int u = v.i;
    return (u16)((u + 0x7fffu + ((u >> 16) & 1u)) >> 16);
}

#if __has_builtin(__builtin_amdgcn_exp2f)
#define EXP2F(x) __builtin_amdgcn_exp2f(x)
#else
#define EXP2F(x) exp2f(x)
#endif

// async global->LDS, 16B per lane; LDS dest = wave-uniform base + lane*16
__device__ __forceinline__ void gload_lds16(const u16* g, void* lds_wave_base) {
    __builtin_amdgcn_global_load_lds(
        (__attribute__((address_space(1))) void*)g,
        (__attribute__((address_space(3))) void*)lds_wave_base,
        16, 0, 0);
}

// counted-vmcnt barrier pair (T4): every wave certifies its own tile loads
// (vmcnt) BEFORE the rendezvous barrier -> after the barrier the whole tile is
// staged. Memory-clobber + sched_barrier fence compiler motion (rule #18).
#define WAITVM(N) asm volatile("s_waitcnt vmcnt(" #N ")" ::: "memory")
#define BARRIER_ACQ()                      \
    do {                                   \
        __builtin_amdgcn_s_barrier();      \
        asm volatile("" ::: "memory");     \
        __builtin_amdgcn_sched_barrier(0); \
    } while (0)
#define BARRIER_REL()                      \
    do {                                   \
        asm volatile("" ::: "memory");     \
        __builtin_amdgcn_s_barrier();      \
    } while (0)

// ---------------------------------------------------------------------------
// Convert+transpose 4 weight matrices (E x E, f32) -> bf16. Wt[n][k]=W[k][n].
// Matrix 0 (Wq) pre-scaled by log2(e)/32 -> attention uses exp2(S) directly.
// ---------------------------------------------------------------------------
__global__ void conv_transpose_k(const float* __restrict__ w0, const float* __restrict__ w1,
                                 const float* __restrict__ w2, const float* __restrict__ w3,
                                 u16* __restrict__ o0, u16* __restrict__ o1,
                                 u16* __restrict__ o2, u16* __restrict__ o3, int n) {
    __shared__ float t[32][33];
    const float* w; u16* o;
    switch (blockIdx.z) {
        case 0: w = w0; o = o0; break;
        case 1: w = w1; o = o1; break;
        case 2: w = w2; o = o2; break;
        default: w = w3; o = o3; break;
    }
    const float sc = (blockIdx.z == 0) ? 0.04508422f : 1.0f;  // log2(e)/32 on Wq
    int tx = threadIdx.x, ty = threadIdx.y;
    int x0 = blockIdx.x * 32, y0 = blockIdx.y * 32;
    t[ty][tx] = w[(size_t)(y0 + ty) * n + x0 + tx];
    __syncthreads();
    o[(size_t)(x0 + ty) * n + y0 + tx] = f2bf(t[tx][ty] * sc);
}

// ---------------------------------------------------------------------------
// Convert f32 -> bf16, vectorized.
// ---------------------------------------------------------------------------
__global__ void conv_k(const float* __restrict__ in, u16* __restrict__ out, int n) {
    int i = (blockIdx.x * blockDim.x + threadIdx.x) * 4;
    if (i >= n) return;
    float4 v = *(const float4*)&in[i];
    ushort4 o;
    o.x = f2bf(v.x); o.y = f2bf(v.y); o.z = f2bf(v.z); o.w = f2bf(v.w);
    *(ushort4*)&out[i] = o;
}

// ---------------------------------------------------------------------------
// Fused QKV GEMM v3: [M,E] @ Wqkv[3E,E]^T.
//  - __launch_bounds__(256,3): 3 blocks/CU.
//  - counted-vmcnt pipeline: STAGE(kt+1); vmcnt(4); barrier; compute; barrier.
//  - LDS-staged coalesced epilogue, V stored directly packed.
// ---------------------------------------------------------------------------
#define QSTG(K0, BUF)                                                          \
    {                                                                          \
        _Pragma("unroll")                                                      \
        for (int it = 0; it < 2; ++it) {                                       \
            int idx = it * 256 + tid;                                          \
            int row = idx >> 2;                                                \
            int c8 = (idx & 3) * 8;                                            \
            size_t ldsoff = (size_t)(it * 256 + wave * 64) * 16;               \
            gload_lds16(&A[(size_t)(bm + row) * K + (K0) + c8],                \
                        (char*)smem + (BUF) * 8192 + ldsoff);                  \
            gload_lds16(&Bt[(size_t)(bn + row) * K + (K0) + c8],               \
                        (char*)smem + 16384 + (BUF) * 8192 + ldsoff);          \
        }                                                                      \
    }

__global__ __launch_bounds__(256, 3) void gemm_qkv(
    const u16* __restrict__ A, const u16* __restrict__ Bt,
    u16* __restrict__ qpk, u16* __restrict__ kpk, u16* __restrict__ vpk,
    int M, int T, int K) {
    __shared__ __align__(16) u16 smem[16384];   // 32 KB: loop = 2x(A,B) bufs; epilogue = [128][128]

    const int tid = threadIdx.x;
    const int lane = tid & 63, wave = tid >> 6;
    const int wm = (wave >> 1) * 64, wn = (wave & 1) * 64;
    const int bm = blockIdx.x * 128, bn = blockIdx.y * 128;
    const int l15 = lane & 15, lq = lane >> 4;

    const int sec = bn >> 10;                 // 0=q,1=k,2=v (uniform per block)
    u16* dst = (sec == 0) ? qpk : (sec == 1) ? kpk : vpk;
    const int bnE = bn & 1023;

    floatx4 acc[4][4];
#pragma unroll
    for (int i = 0; i < 4; ++i)
#pragma unroll
        for (int j = 0; j < 4; ++j) acc[i][j] = (floatx4)0.0f;

    const int nkt = K / 32;
    QSTG(0, 0);

    for (int kt = 0; kt < nkt; ++kt) {
        const int cur = kt & 1;
        if (kt + 1 < nkt) {
            QSTG((kt + 1) * 32, cur ^ 1);
            WAITVM(4);                       // tile kt staged; kt+1 in flight
        } else {
            WAITVM(0);
        }
        BARRIER_ACQ();

        const u16* la = smem + cur * 4096;
        const u16* lb = smem + 8192 + cur * 4096;
        short8 af[4], bfr[4];
#pragma unroll
        for (int i = 0; i < 4; ++i) af[i] = *(const short8*)&la[(wm + i * 16 + l15) * 32 + lq * 8];
#pragma unroll
        for (int j = 0; j < 4; ++j) bfr[j] = *(const short8*)&lb[(wn + j * 16 + l15) * 32 + lq * 8];

#pragma unroll
        for (int i = 0; i < 4; ++i)
#pragma unroll
            for (int j = 0; j < 4; ++j)
                acc[i][j] = __builtin_amdgcn_mfma_f32_16x16x32_bf16(af[i], bfr[j], acc[i][j], 0, 0, 0);

        BARRIER_REL();   // all reads of buf cur done before iter kt+1 overwrites it
    }

    // ---- epilogue: stage C tile in LDS, coalesced 16B stores ----
    if (sec < 2) {
        // row-major staging [t_loc][colE_loc], swizzled
#pragma unroll
        for (int i = 0; i < 4; ++i)
#pragma unroll
            for (int r = 0; r < 4; ++r) {
                int trow = wm + i * 16 + lq * 4 + r;
                int s7 = ((trow >> 2) & 7) << 4;
#pragma unroll
                for (int j = 0; j < 4; ++j) {
                    int col = wn + j * 16 + l15;
                    smem[trow * 128 + (col ^ s7)] = f2bf(acc[i][j][r]);
                }
            }
        __syncthreads();
        const int rg = tid >> 3, cc = tid & 7;
#pragma unroll
        for (int p = 0; p < 4; ++p)
#pragma unroll
            for (int sfx = 0; sfx < 2; ++sfx) {
                int row = p * 32 + rg;
                int ch = cc + sfx * 8;
                short8 v = *(const short8*)&smem[row * 128 + ((ch * 8) ^ (((row >> 2) & 7) << 4))];
                int colE = bnE + ch * 8;
                int h = colE >> 6, d = colE & 63;
                int rowg = bm + row;
                int b = rowg >> 11, t = rowg & 2047;
                *(short8*)&dst[(((size_t)(b * 16 + h) * T) + t) * 64 + d] = v;
            }
    } else {
        // V: transposed staging [colE_loc][t_loc]; store packed [bh][kblk][d][tloc]
#pragma unroll
        for (int j = 0; j < 4; ++j) {
            int clo = wn + j * 16 + l15;
            int s7 = ((clo >> 2) & 7) << 4;
#pragma unroll
            for (int i = 0; i < 4; ++i)
#pragma unroll
                for (int r = 0; r < 4; ++r) {
                    int trow = wm + i * 16 + lq * 4 + r;
                    smem[clo * 128 + (trow ^ s7)] = f2bf(acc[i][j][r]);
                }
        }
        __syncthreads();
        const int rg = tid >> 3, cc = tid & 7;
        const int b = bm >> 11;
#pragma unroll
        for (int p = 0; p < 4; ++p)
#pragma unroll
            for (int sfx = 0; sfx < 2; ++sfx) {
                int clo = p * 32 + rg;
                int ch = cc + sfx * 8;                 // t-chunk
                short8 v = *(const short8*)&smem[clo * 128 + ((ch * 8) ^ (((clo >> 2) & 7) << 4))];
                int colE = bnE + clo;
                int h = colE >> 6, d = colE & 63;
                int t = (bm + ch * 8) & 2047;
                int kblk = t >> 6, tloc = t & 63;
                *(short8*)&dst[(((size_t)(b * 16 + h) * 32 + kblk) * 64 + d) * 64 + tloc] = v;
            }
    }
}

// ---------------------------------------------------------------------------
// FF GEMM v3: 64x128 tile, counted-vmcnt double-buffered staging (3 loads/
// thread/tile -> vmcnt(3)). Cf (f32) = bf2f(resid) + relu(acc + bias[col]).
// ---------------------------------------------------------------------------
#define FSTG(K0, BUF)                                                          \
    {                                                                          \
        {                                                                      \
            int row = tid >> 2;                                                \
            int c8 = (tid & 3) * 8;                                            \
            size_t ldsoff = (size_t)(wave * 64) * 16;                          \
            gload_lds16(&A[(size_t)(bm + row) * K + (K0) + c8],                \
                        (char*)smemF + (BUF) * 4096 + ldsoff);                 \
        }                                                                      \
        _Pragma("unroll")                                                      \
        for (int it = 0; it < 2; ++it) {                                       \
            int idx = it * 256 + tid;                                          \
            int row = idx >> 2;                                                \
            int c8 = (idx & 3) * 8;                                            \
            size_t ldsoff = (size_t)(it * 256 + wave * 64) * 16;               \
            gload_lds16(&Bt[(size_t)(bn + row) * K + (K0) + c8],               \
                        (char*)smemF + 8192 + (BUF) * 8192 + ldsoff);          \
        }                                                                      \
    }

__global__ __launch_bounds__(256) void gemm64_bt(
    const u16* __restrict__ A, const u16* __restrict__ Bt, float* __restrict__ Cf,
    const float* __restrict__ bias, const u16* __restrict__ resid,
    int M, int N, int K) {
    __shared__ __align__(16) u16 smemF[12288];  // 24 KB: A 2x(64x32), B 2x(128x32)

    const int tid = threadIdx.x;
    const int lane = tid & 63, wave = tid >> 6;
    const int wm = (wave >> 1) * 32, wn = (wave & 1) * 64;
    const int bm = blockIdx.x * 64, bn = blockIdx.y * 128;
    const int l15 = lane & 15, lq = lane >> 4;

    floatx4 acc[2][4];
#pragma unroll
    for (int i = 0; i < 2; ++i)
#pragma unroll
        for (int j = 0; j < 4; ++j) acc[i][j] = (floatx4)0.0f;

    const int nkt = K / 32;
    FSTG(0, 0);

    for (int kt = 0; kt < nkt; ++kt) {
        const int cur = kt & 1;
        if (kt + 1 < nkt) {
            FSTG((kt + 1) * 32, cur ^ 1);
            WAITVM(3);                       // tile kt staged; kt+1 in flight
        } else {
            WAITVM(0);
        }
        BARRIER_ACQ();

        const u16* la = smemF + cur * 2048;
        const u16* lb = smemF + 4096 + cur * 2048 * 2;
        short8 af[2], bfr[4];
#pragma unroll
        for (int i = 0; i < 2; ++i) af[i] = *(const short8*)&la[(wm + i * 16 + l15) * 32 + lq * 8];
#pragma unroll
        for (int j = 0; j < 4; ++j) bfr[j] = *(const short8*)&lb[(wn + j * 16 + l15) * 32 + lq * 8];

#pragma unroll
        for (int i = 0; i < 2; ++i)
#pragma unroll
            for (int j = 0; j < 4; ++j)
                acc[i][j] = __builtin_amdgcn_mfma_f32_16x16x32_bf16(af[i], bfr[j], acc[i][j], 0, 0, 0);

        BARRIER_REL();
    }

#pragma unroll
    for (int i = 0; i < 2; ++i)
#pragma unroll
        for (int j = 0; j < 4; ++j)
#pragma unroll
            for (int r = 0; r < 4; ++r) {
                int row = bm + wm + i * 16 + lq * 4 + r;
                int col = bn + wn + j * 16 + l15;
                float v = acc[i][j][r];
                v = fmaxf(v + bias[col], 0.0f) + bf2f(resid[(size_t)row * N + col]);
                Cf[(size_t)row * N + col] = v;
            }
}

// ---------------------------------------------------------------------------
// Flash attention v18 (session-best config): attn11 body, plain LPT
// qb = 31-by, counted-vmcnt staging, occupancy throttled to 3 blocks/CU via
// +20 KB dynamic LDS (768 slots < 1024 blocks -> backfill sustains
// residency). Nine structural experiments confirmed this as the local
// optimum for this workload.
// ---------------------------------------------------------------------------
#define STAGE(KT, BUF)                                                            \
    {                                                                             \
        const u16* kc_ = kb + (size_t)((KT) * 64 + r0) * 64 + swz0;               \
        gload_lds16(kc_, (char*)kbuf + (BUF) * 8192 + wave * 1024);               \
        gload_lds16(kc_ + 32 * 64, (char*)kbuf + (BUF) * 8192 + 4096 + wave * 1024); \
        const u16* vc_ = vp + (size_t)(KT) * 4096 + r0 * 64 + swz0;               \
        gload_lds16(vc_, (char*)vbuf + (BUF) * 8192 + wave * 1024);               \
        gload_lds16(vc_ + 32 * 64, (char*)vbuf + (BUF) * 8192 + 4096 + wave * 1024); \
    }

__global__ __launch_bounds__(256) void attn18_k(
    const u16* __restrict__ qpk, const u16* __restrict__ kpk,
    const u16* __restrict__ vpack, const float* __restrict__ xf,
    u16* __restrict__ y, int T, int E) {
    __shared__ u16 kbuf[2][64 * 64];        // double-buffered, f-swizzled slots
    __shared__ u16 vbuf[2][64 * 64];
    // +20 KB dynamic LDS requested at launch -> 52 KB/block -> 3 blocks/CU

    const int tid = threadIdx.x;
    const int lane = tid & 63, wave = tid >> 6;
    const int l15 = lane & 15, lq = lane >> 4;
    const int bh = blockIdx.x;              // grid.x = 32 -> head-per-XCD affinity
    const int b = bh >> 4, h = bh & 15;
    const int qb = 31 - (int)blockIdx.y;    // LPT: longest blocks dispatch first

    const u16* qp = qpk + (size_t)bh * T * 64;
    const u16* kb = kpk + (size_t)bh * T * 64;
    const u16* vp = vpack + (size_t)bh * T * 64;    // [T/64][64][64] blocks

    const int r0 = tid >> 3;            // staging row 0..31
    const int slot = tid & 7;           // staging 16B slot within row
    const int fr0 = (r0 & 3) | (((r0 >> 3) & 1) << 2);
    const int swz0 = ((slot - fr0) & 7) * 8;        // source col elems (swizzle)

    // K-row permutation: MFMA t2 row i holds k = (i>>2)*8+(t2&1)*4+(i&3)+(t2>>1)*32
    const int rbase = ((l15 >> 2) * 8) + (l15 & 3);
    const int sA = lq + (l15 & 7);                           // K read slot base
    const int sB = lq + ((l15 & 3) | (((l15 >> 3) & 1) << 2)); // V read slot base

    const int qt = qb * 64 + wave * 16;     // this wave's 16 q-rows
    const int qg = qt + l15;                // lane's q-row in S^T layout
    const int nkb = qb + 1;

    short8 aq[2];
#pragma unroll
    for (int c = 0; c < 2; ++c)
        aq[c] = *(const short8*)&qp[(size_t)qg * 64 + c * 32 + lq * 8];

    floatx4 o[4];
#pragma unroll
    for (int n = 0; n < 4; ++n) o[n] = (floatx4)0.0f;
    float lsum = 0.0f;

    // prologue: stage chunk 0 into buffer 0 (waited inside the loop)
    STAGE(0, 0);

#pragma unroll 1
    for (int kt = 0; kt < nkb; ++kt) {
        const int kc0 = kt * 64;
        const int cur = kt & 1;
        const int curoff = cur * 8192;   // byte offset into kbuf/vbuf

        // issue DMA for next chunk into the alternate buffer, then wait only
        // for the CURRENT chunk's loads (issued a full iteration ago)
        if (kt + 1 < nkb) {
            STAGE(kt + 1, cur ^ 1);
            WAITVM(4);
        } else {
            WAITVM(0);
        }
        BARRIER_ACQ();

        // ---- S^T = K Q^T (rows = permuted k, cols = q) ----
        floatx4 st[4];
        __builtin_amdgcn_s_setprio(1);
#pragma unroll
        for (int t2 = 0; t2 < 4; ++t2) {
            const int row = rbase + (t2 & 1) * 4 + (t2 >> 1) * 32;
            floatx4 sa = (floatx4)0.0f;
#pragma unroll
            for (int c = 0; c < 2; ++c) {
                int off = row * 128 + ((c * 4 + sA) & 7) * 16;
                short8 bk = *(const short8*)((const char*)kbuf + curoff + off);
                sa = __builtin_amdgcn_mfma_f32_16x16x32_bf16(bk, aq[c], sa, 0, 0, 0);
            }
            st[t2] = sa;
        }
        __builtin_amdgcn_s_setprio(0);

        // ---- softmax numerator (Q pre-scaled -> exp2 direct), pack in-reg ----
        const bool partial = (kt == qb);   // block-uniform: only diagonal chunk
        unsigned int pw[8];
#pragma unroll
        for (int t2 = 0; t2 < 4; ++t2) {
            float e0, e1, e2, e3;
            const int kg0 = kc0 + lq * 8 + (t2 & 1) * 4 + ((t2 >> 1) * 32);
            if (partial) {
                e0 = (kg0 + 0 <= qg) ? EXP2F(st[t2][0]) : 0.0f;
                e1 = (kg0 + 1 <= qg) ? EXP2F(st[t2][1]) : 0.0f;
                e2 = (kg0 + 2 <= qg) ? EXP2F(st[t2][2]) : 0.0f;
                e3 = (kg0 + 3 <= qg) ? EXP2F(st[t2][3]) : 0.0f;
            } else {
                e0 = EXP2F(st[t2][0]);
                e1 = EXP2F(st[t2][1]);
                e2 = EXP2F(st[t2][2]);
                e3 = EXP2F(st[t2][3]);
            }
            lsum += (e0 + e1) + (e2 + e3);
            unsigned int w0, w1;
            asm("v_cvt_pk_bf16_f32 %0, %1, %2" : "=v"(w0) : "v"(e0), "v"(e1));
            asm("v_cvt_pk_bf16_f32 %0, %1, %2" : "=v"(w1) : "v"(e2), "v"(e3));
            pw[t2 * 2 + 0] = w0;
            pw[t2 * 2 + 1] = w1;
        }

        // ---- O += P @ V (P already lane-local in A-fragment layout) ----
        __builtin_amdgcn_s_setprio(1);
#pragma unroll
        for (int kc = 0; kc < 2; ++kc) {
            union { unsigned int u[4]; short8 s; } ap;
            ap.u[0] = pw[kc * 4 + 0];
            ap.u[1] = pw[kc * 4 + 1];
            ap.u[2] = pw[kc * 4 + 2];
            ap.u[3] = pw[kc * 4 + 3];
#pragma unroll
            for (int n = 0; n < 4; ++n) {
                int off = (n * 16 + l15) * 128 + ((kc * 4 + sB) & 7) * 16;
                short8 bv = *(const short8*)((const char*)vbuf + curoff + off);
                o[n] = __builtin_amdgcn_mfma_f32_16x16x32_bf16(ap.s, bv, o[n], 0, 0, 0);
            }
        }
        __builtin_amdgcn_s_setprio(0);

        BARRIER_REL();   // readers of buf cur done before next iter overwrites
    }

    // ---- row-sum reduce across lq groups + redistribute to O rows ----
    lsum += __shfl_xor(lsum, 16, 64);
    lsum += __shfl_xor(lsum, 32, 64);

    const float* xp = xf + (size_t)b * T * E + (size_t)h * 64;
    u16* yp = y + (size_t)b * T * E + (size_t)h * 64;
    float rl[4];
#pragma unroll
    for (int r = 0; r < 4; ++r) rl[r] = 1.0f / __shfl(lsum, lq * 4 + r, 64);
#pragma unroll
    for (int n = 0; n < 4; ++n)
#pragma unroll
        for (int r = 0; r < 4; ++r) {
            int rowg = qt + lq * 4 + r;
            int col = n * 16 + l15;
            float val = o[n][r] * rl[r];
            float res = __builtin_nontemporal_load(xp + (size_t)rowg * E + col);
            yp[(size_t)rowg * E + col] = f2bf(res + val);
        }
}

// ---------------------------------------------------------------------------
extern "C" void kernel_launch(void* const* d_in, const int* in_sizes, int n_in,
                              void* d_out, int out_size, void* d_ws, size_t ws_size,
                              hipStream_t stream) {
    const int B = 2, T = 2048, E = 1024;
    const int M = B * T;  // 4096

    const float* x  = (const float*)d_in[0];
    const float* Wq = (const float*)d_in[1];
    const float* Wk = (const float*)d_in[2];
    const float* Wv = (const float*)d_in[3];
    const float* Wf = (const float*)d_in[4];
    const float* bf = (const float*)d_in[5];
    float* out = (float*)d_out;

    u16* ws = (u16*)d_ws;
    const size_t WN = (size_t)E * E;      // 1M elems per weight
    const size_t XN = (size_t)M * E;      // 4M elems per activation
    u16* Wqkv  = ws;                       // [3E][E] fused transposed weights
    u16* WfT   = ws + 3 * WN;
    u16* xb    = ws + 4 * WN;              // A input (bf16 x)
    u16* qpk   = ws + 4 * WN + XN;         // per-head dense q [bh][t][64]
    u16* kpk   = ws + 4 * WN + 2 * XN;     // per-head dense k
    u16* vpk   = ws + 4 * WN + 3 * XN;     // packed v [bh][T/64][64][64]
    u16* yb    = ws + 4 * WN + 4 * XN;
    // total: 4*WN + 5*XN = 48 MB

    conv_transpose_k<<<dim3(E / 32, E / 32, 4), dim3(32, 32), 0, stream>>>(
        Wq, Wk, Wv, Wf, Wqkv, Wqkv + WN, Wqkv + 2 * WN, WfT, E);
    conv_k<<<(int)(XN / 1024), 256, 0, stream>>>(x, xb, (int)XN);

    // fused QKV projection: q/k per-head dense, v directly packed (no vpack)
    gemm_qkv<<<dim3(M / 128, 3 * E / 128), 256, 0, stream>>>(
        xb, Wqkv, qpk, kpk, vpk, M, T, E);

    // grid (bh=32, qb=32), LPT; +20 KB dynamic LDS throttles to 3 blocks/CU
    // (768 slots < 1024 blocks -> backfill sustains residency)
    attn18_k<<<dim3(B * 16, T / 64), 256, 20480, stream>>>(qpk, kpk, vpk, x, yb, T, E);

    // FF: out = yb + relu(yb @ Wf + bf)
    gemm64_bt<<<dim3(M / 64, E / 128), 256, 0, stream>>>(yb, WfT, out, bf, yb, M, E, E);
}